// Round 13
// baseline (121.329 us; speedup 1.0000x reference)
//
#include <hip/hip_runtime.h>
#include <hip/hip_bf16.h>

#define B_ 64
#define J_ 2048
#define K_ 32
#define D_ 16
#define KD 512
#define CHB 32       // k_B j-chunks (spart partials)
#define JCB 64       // j's per k_B chunk

typedef __attribute__((ext_vector_type(8))) short short8v;    // 8 bf16 (4 VGPR)
typedef __attribute__((ext_vector_type(4))) float f32x4;      // 4 f32 acc
typedef __attribute__((ext_vector_type(16))) float f32x16;    // 16 f32 acc (32x32)

__device__ __forceinline__ float bf2f(unsigned int bits16) {
  unsigned int u = bits16 << 16;
  return __builtin_bit_cast(float, u);
}
__device__ __forceinline__ unsigned int f2bf(float f) {
  unsigned int u = __builtin_bit_cast(unsigned int, f);
  u = u + 0x7fffu + ((u >> 16) & 1u);   // round-to-nearest-even
  return u >> 16;
}
// HW packed f32->bf16 pair convert (gfx950; no builtin -- inline asm). lo -> low16.
__device__ __forceinline__ unsigned int cvtpk(float lo, float hi) {
  unsigned int r;
  asm("v_cvt_pk_bf16_f32 %0, %1, %2" : "=v"(r) : "v"(lo), "v"(hi));
  return r;
}
// (bf16,bf16) dword * scalar c -> (bf16,bf16) dword
__device__ __forceinline__ unsigned int pkmul(unsigned int w, float c) {
  const float lo = __builtin_bit_cast(float, w << 16) * c;
  const float hi = __builtin_bit_cast(float, w & 0xffff0000u) * c;
  return cvtpk(lo, hi);
}
__device__ __forceinline__ short8v mk_frag4(unsigned int d0, unsigned int d1,
                                            unsigned int d2, unsigned int d3) {
  uint4 t = make_uint4(d0, d1, d2, d3);        // slots 0-3 = j0, 4-7 = j1
  return __builtin_bit_cast(short8v, t);
}
__device__ __forceinline__ f32x16 zero16() {
  f32x16 z;
#pragma unroll
  for (int i = 0; i < 16; ++i) z[i] = 0.f;
  return z;
}

// ---------------- prep: WB[j][k][d][i] = bf16(W[k][j][d][i]);  XT[j][b][i] = bf16(x[b][j][i])
// Pure streaming (HBM-bound), cvt via v_cvt_pk_bf16_f32.
__global__ __launch_bounds__(256) void k_prep(const float* __restrict__ inp,
                                              const float* __restrict__ W,
                                              unsigned short* __restrict__ WB,
                                              unsigned short* __restrict__ XT) {
  const size_t tid = (size_t)blockIdx.x * 256 + threadIdx.x;
  const size_t stride = (size_t)gridDim.x * 256;
  for (size_t g8 = tid; g8 < (size_t)J_ * K_ * 32; g8 += stride) {
    const size_t o = g8 * 8;
    const int j = (int)(o >> 13), k = (int)((o >> 8) & 31), di = (int)(o & 255);
    const float* src = W + ((size_t)k * J_ + j) * 256 + di;
    const float4 a = *(const float4*)src;
    const float4 b = *(const float4*)(src + 4);
    uint4 pk;
    pk.x = cvtpk(a.x, a.y);
    pk.y = cvtpk(a.z, a.w);
    pk.z = cvtpk(b.x, b.y);
    pk.w = cvtpk(b.z, b.w);
    *(uint4*)(WB + o) = pk;
  }
  for (size_t g8 = tid; g8 < (size_t)J_ * B_ * 2; g8 += stride) {
    const size_t o = g8 * 8;
    const int j = (int)(o >> 10), b = (int)((o >> 4) & 63), i0 = (int)(o & 15);
    const float* src = inp + ((size_t)b * J_ + j) * 16 + i0;
    const float4 a = *(const float4*)src;
    const float4 c = *(const float4*)(src + 4);
    uint4 pk;
    pk.x = cvtpk(a.x, a.y);
    pk.y = cvtpk(a.z, a.w);
    pk.z = cvtpk(c.x, c.y);
    pk.w = cvtpk(c.z, c.w);
    *(uint4*)(XT + o) = pk;
  }
}

// ---------------- k_B0: iter-0 s-partials (c = 1/32) from WB bf16 (r11-proven shape).
// Grid 1024. Block = (ch, k); 64 j's in 4 batches of 16; one 32-load window per batch.
__global__ __launch_bounds__(256, 4) void k_B0(const unsigned short* __restrict__ XT,
                                               const unsigned short* __restrict__ WB,
                                               float* __restrict__ spart) {
  const int x = blockIdx.x;
  const int ch = x >> 5, k = x & 31;
  const int t = threadIdx.x;
  const int wave = t >> 6, lane = t & 63;
  const int g = lane >> 4, r = lane & 15;
  const int b = wave * 16 + r;
  const int j0 = ch * JCB;

  const unsigned short* wp = WB + ((size_t)j0 * 32 + k) * 256 + r * 16 + 4 * g;
  const unsigned short* xp = XT + ((size_t)j0 * 64 + b) * 16 + 4 * g;

  f32x4 acc = {0.f, 0.f, 0.f, 0.f};
#pragma unroll
  for (int batch = 0; batch < 4; ++batch) {
    const int jb0 = batch * 16;
    uint2 wv[16], xv[16];
#pragma unroll
    for (int jc = 0; jc < 16; ++jc)
      wv[jc] = *(const uint2*)(wp + (size_t)(jb0 + jc) * 8192);
#pragma unroll
    for (int jc = 0; jc < 16; ++jc)
      xv[jc] = *(const uint2*)(xp + (size_t)(jb0 + jc) * 1024);
#pragma unroll
    for (int jp = 0; jp < 8; ++jp) {
      const int ja = 2 * jp, jb2 = 2 * jp + 1;
      acc = __builtin_amdgcn_mfma_f32_16x16x32_bf16(
          mk_frag4(wv[ja].x, wv[ja].y, wv[jb2].x, wv[jb2].y),
          mk_frag4(xv[ja].x, xv[ja].y, xv[jb2].x, xv[jb2].y), acc, 0, 0, 0);
    }
  }
  // C layout: col = b (lane&15), row = d = 4g + reg  ->  16B contiguous store
  *(float4*)(spart + (((size_t)b * CHB + ch) * 32 + k) * 16 + 4 * g) =
      make_float4(acc[0] * (1.f / 32.f), acc[1] * (1.f / 32.f),
                  acc[2] * (1.f / 32.f), acc[3] * (1.f / 32.f));
}

// ---------------- k_A (32x32 MFMA): c[j][k][b] = softmax_k(osum . u_hat) directly.
// Block = 4 j's, grid 512. Wave = (jg, bt) handles 2 j's; os loaded+decoded once per
// k-pair, reused by both j. In-register softmax over 32 k; direct c store.
__global__ __launch_bounds__(256, 2) void k_A(const unsigned short* __restrict__ XT,
                                              const unsigned short* __restrict__ WB,
                                              const unsigned short* __restrict__ osB,
                                              float* __restrict__ cT) {
  const int jb = blockIdx.x;
  const int t = threadIdx.x;
  const int wave = t >> 6, lane = t & 63;
  const int jg = wave >> 1, bt = wave & 1;
  const int jB = jb * 4 + jg * 2;              // wave's j's: jB, jB+1
  const int hi = lane >> 5, b31 = lane & 31;
  const int b = bt * 32 + b31;

  short8v xf[2];
#pragma unroll
  for (int jj = 0; jj < 2; ++jj)
    xf[jj] = __builtin_bit_cast(short8v,
        *(const uint4*)(XT + (size_t)(jB + jj) * 1024 + b * 16 + 8 * hi));

  const unsigned short* wa0 =
      WB + (size_t)jB * 8192 + (b31 >> 4) * 256 + (b31 & 15) * 16 + 8 * hi;
  const unsigned short* osb = osB + ((size_t)bt * 64 + lane) * 8;   // + k*1024

  float S[2] = {0.f, 0.f};
  unsigned int e_pk[2][16];                    // bf16-packed e for k = 2tp, 2tp+1

#pragma unroll
  for (int grp = 0; grp < 4; ++grp) {
    uint4 os0[4], os1[4], av[2][4];
#pragma unroll
    for (int q = 0; q < 4; ++q) {
      const int tp = grp * 4 + q;
      os0[q] = *(const uint4*)(osb + (size_t)(2 * tp) * 1024);
      os1[q] = *(const uint4*)(osb + (size_t)(2 * tp + 1) * 1024);
      av[0][q] = *(const uint4*)(wa0 + (size_t)tp * 512);
      av[1][q] = *(const uint4*)(wa0 + 8192 + (size_t)tp * 512);
    }
#pragma unroll
    for (int q = 0; q < 4; ++q) {
      const int tp = grp * 4 + q;
      const unsigned int* o0 = (const unsigned int*)&os0[q];
      const unsigned int* o1 = (const unsigned int*)&os1[q];
      float f0v[8], f1v[8];
#pragma unroll
      for (int s = 0; s < 8; ++s) {
        const unsigned int w0 = o0[s >> 1], w1 = o1[s >> 1];
        f0v[s] = bf2f((s & 1) ? (w0 >> 16) : (w0 & 0xffffu));
        f1v[s] = bf2f((s & 1) ? (w1 >> 16) : (w1 & 0xffffu));
      }
#pragma unroll
      for (int jj = 0; jj < 2; ++jj) {
        const f32x16 u = __builtin_amdgcn_mfma_f32_32x32x16_bf16(
            __builtin_bit_cast(short8v, av[jj][q]), xf[jj], zero16(), 0, 0, 0);
        float pe = 0.f, po = 0.f;
#pragma unroll
        for (int s = 0; s < 8; ++s) {
          pe = fmaf(u[s], f0v[s], pe);       // regs 0-7: k even, d=(s&3)+4hi+8*(s>>2)
          po = fmaf(u[8 + s], f1v[s], po);   // regs 8-15: k odd
        }
        pe += __shfl_xor(pe, 32);            // partner hi-half: full dot over d
        po += __shfl_xor(po, 32);
        // logits O(+-8): skip max-subtraction (shift-invariant; validated r1-r12)
        const float ee = __expf(pe), eo = __expf(po);
        S[jj] += ee + eo;
        e_pk[jj][tp] = cvtpk(ee, eo);
      }
    }
  }

  if (hi == 0) {                             // lanes 0-31: b-contiguous 128B stores
#pragma unroll
    for (int jj = 0; jj < 2; ++jj) {
      const float rS = __builtin_amdgcn_rcpf(S[jj]);
      float* cp = cT + (size_t)(jB + jj) * 2048 + b;      // + k*64
#pragma unroll
      for (int tp = 0; tp < 16; ++tp) {
        cp[(size_t)(2 * tp) * 64]     = bf2f(e_pk[jj][tp] & 0xffffu) * rS;
        cp[(size_t)(2 * tp + 1) * 64] = bf2f(e_pk[jj][tp] >> 16) * rS;
      }
    }
  }
}

// ---------------- k_B1: s-partials via MFMA, c folded into B-frag (pkmul+cvt_pk).
// COUT=1: blocks >= 1024 instead run the c-transpose into outp (fused k_cout).
template <int COUT>
__global__ __launch_bounds__(256, 4) void k_B1(const unsigned short* __restrict__ XT,
                                               const unsigned short* __restrict__ WB,
                                               const float* __restrict__ cT,
                                               float* __restrict__ spart,
                                               float* __restrict__ outp) {
  __shared__ float lds[COUT ? 64 * 129 : 1];
  if (COUT && blockIdx.x >= 1024) {
    // ---- fused k_cout: cT[j][k][b] -> outp[b][k][16+j]
    const int bx = blockIdx.x - 1024;
    const int k = bx & 31, j0 = (bx >> 5) * 128;
    const int t = threadIdx.x;
#pragma unroll
    for (int m = 0; m < 32; ++m) {
      const int jj = m * 4 + (t >> 6), b = t & 63;
      lds[b * 129 + jj] = cT[((size_t)(j0 + jj) * 32 + k) * 64 + b];  // coalesced
    }
    __syncthreads();
#pragma unroll
    for (int m = 0; m < 8; ++m) {
      const int b = m * 8 + (t >> 5), jq = (t & 31) * 4;
      *(float4*)(outp + ((size_t)b * 32 + k) * 2064 + 16 + j0 + jq) =
          make_float4(lds[b * 129 + jq], lds[b * 129 + jq + 1],
                      lds[b * 129 + jq + 2], lds[b * 129 + jq + 3]);
    }
    return;
  }

  const int x = blockIdx.x;
  const int ch = x >> 5, k = x & 31;
  const int t = threadIdx.x;
  const int wave = t >> 6, lane = t & 63;
  const int g = lane >> 4, r = lane & 15;
  const int b = wave * 16 + r;
  const int j0 = ch * JCB;

  const unsigned short* wp = WB + ((size_t)j0 * 32 + k) * 256 + r * 16 + 4 * g;
  const unsigned short* xp = XT + ((size_t)j0 * 64 + b) * 16 + 4 * g;
  const float* cp = cT + ((size_t)j0 * 32 + k) * 64 + b;

  f32x4 acc = {0.f, 0.f, 0.f, 0.f};
#pragma unroll
  for (int batch = 0; batch < 4; ++batch) {
    const int jb0 = batch * 16;
    uint2 wv[16], xv[16];
    float cv[16];
#pragma unroll
    for (int jc = 0; jc < 16; ++jc)
      wv[jc] = *(const uint2*)(wp + (size_t)(jb0 + jc) * 8192);
#pragma unroll
    for (int jc = 0; jc < 16; ++jc)
      xv[jc] = *(const uint2*)(xp + (size_t)(jb0 + jc) * 1024);
#pragma unroll
    for (int jc = 0; jc < 16; ++jc) cv[jc] = cp[(size_t)(jb0 + jc) * 2048];
#pragma unroll
    for (int jp = 0; jp < 8; ++jp) {
      const int ja = 2 * jp, jb2 = 2 * jp + 1;
      const float ca = cv[ja], cb = cv[jb2];
      acc = __builtin_amdgcn_mfma_f32_16x16x32_bf16(
          mk_frag4(wv[ja].x, wv[ja].y, wv[jb2].x, wv[jb2].y),
          mk_frag4(pkmul(xv[ja].x, ca), pkmul(xv[ja].y, ca),
                   pkmul(xv[jb2].x, cb), pkmul(xv[jb2].y, cb)),
          acc, 0, 0, 0);
    }
  }
  *(float4*)(spart + (((size_t)b * CHB + ch) * 32 + k) * 16 + 4 * g) =
      make_float4(acc[0], acc[1], acc[2], acc[3]);
}

// ---------------- squash: reduce spart -> s, squash -> o; f32 osum master +
// bf16 osB mirror in k_A's fragment layout [k][bt][hi*32+b31][slot].
__global__ __launch_bounds__(256) void k_squash(const float* __restrict__ spart,
                                                float* __restrict__ osum,
                                                unsigned short* __restrict__ osB,
                                                float* __restrict__ outp,
                                                int first, int final_) {
  const int t = threadIdx.x;
  const int wave = t >> 6, lane = t & 63;
  const int gw = blockIdx.x * 4 + wave;   // 0..B_*K_-1
  const int b = gw >> 5, k = gw & 31;
  const int d = lane & 15, pg = lane >> 4;
  float s = 0.f;
#pragma unroll
  for (int p = pg; p < CHB; p += 4)
    s += spart[(((size_t)b * CHB + p) * 32 + k) * 16 + d];
  s += __shfl_xor(s, 16);
  s += __shfl_xor(s, 32);
  float ss = s * s;
  ss += __shfl_xor(ss, 1); ss += __shfl_xor(ss, 2);
  ss += __shfl_xor(ss, 4); ss += __shfl_xor(ss, 8);
  const float scale = (ss / (1.f + ss)) * rsqrtf(ss + 1e-7f);
  const float ov = scale * s;
  if (final_) {
    if (lane < 16) outp[((size_t)b * K_ + k) * 2064 + d] = ov;
  } else {
    const float prev = first ? 0.f : osum[b * KD + k * 16 + d];
    const float ns = prev + ov;
    if (lane < 16) {
      osum[b * KD + k * 16 + d] = ns;
      // osB scatter: d -> (hi, slot): hi = (d>>2)&1, slot = (d&3) + 4*(d>>3)
      const int hi = (d >> 2) & 1;
      const int slot = (d & 3) + ((d >> 3) << 2);
      osB[(((size_t)k * 2 + (b >> 5)) * 64 + hi * 32 + (b & 31)) * 8 + slot] = f2bf(ns);
    }
  }
}

extern "C" void kernel_launch(void* const* d_in, const int* in_sizes, int n_in,
                              void* d_out, int out_size, void* d_ws, size_t ws_size,
                              hipStream_t stream) {
  const float* inp = (const float*)d_in[0];   // [64,2048,16]
  const float* W   = (const float*)d_in[1];   // [32,2048,16,16]
  float* outp = (float*)d_out;                // [64,32,2064]
  char* ws = (char*)d_ws;
  // ws: WB 32M | XT 4M | cT 16M | spart 16M region | osum 128K | osB 64K
  unsigned short* WB = (unsigned short*)ws;
  unsigned short* XT = (unsigned short*)(ws + (size_t)33554432);
  float* cT    = (float*)(ws + (size_t)33554432 + 4194304);
  float* spart = (float*)(ws + (size_t)33554432 + 4194304 + 16777216);
  float* osum  = (float*)(ws + (size_t)33554432 + 4194304 + 16777216 + 16777216);
  unsigned short* osB =
      (unsigned short*)(ws + (size_t)33554432 + 4194304 + 16777216 + 16777216 + 131072);

  k_prep<<<2048, 256, 0, stream>>>(inp, W, WB, XT);
  // iter 0: c = 1/32
  k_B0<<<CHB * K_, 256, 0, stream>>>(XT, WB, spart);
  k_squash<<<B_ * K_ / 4, 256, 0, stream>>>(spart, osum, osB, outp, 1, 0);
  // iter 1
  k_A<<<J_ / 4, 256, 0, stream>>>(XT, WB, osB, cT);
  k_B1<0><<<CHB * K_, 256, 0, stream>>>(XT, WB, cT, spart, nullptr);
  k_squash<<<B_ * K_ / 4, 256, 0, stream>>>(spart, osum, osB, outp, 0, 0);
  // iter 2 (final): k_B1<1> also transposes c into outp (blocks >= 1024)
  k_A<<<J_ / 4, 256, 0, stream>>>(XT, WB, osB, cT);
  k_B1<1><<<CHB * K_ + 512, 256, 0, stream>>>(XT, WB, cT, spart, outp);
  k_squash<<<B_ * K_ / 4, 256, 0, stream>>>(spart, osum, osB, outp, 0, 1);
}

// Round 14
// 105.446 us; speedup vs baseline: 1.1506x; 1.1506x over previous
//
#include <hip/hip_runtime.h>
#include <hip/hip_bf16.h>

#define B_ 64
#define J_ 2048
#define K_ 32
#define D_ 16
#define KD 512
#define NCH 256      // j-chunks (spart partial depth)
#define JCR 8        // j's per k_R block

typedef __attribute__((ext_vector_type(8))) short short8v;    // 8 bf16 (4 VGPR)
typedef __attribute__((ext_vector_type(16))) float f32x16;    // 16 f32 acc (32x32)

__device__ __forceinline__ float bf2f(unsigned int bits16) {
  unsigned int u = bits16 << 16;
  return __builtin_bit_cast(float, u);
}
__device__ __forceinline__ unsigned int f2bf(float f) {
  unsigned int u = __builtin_bit_cast(unsigned int, f);
  u = u + 0x7fffu + ((u >> 16) & 1u);   // round-to-nearest-even
  return u >> 16;
}
// HW packed f32->bf16 pair convert (gfx950; no builtin -- inline asm). lo -> low16.
__device__ __forceinline__ unsigned int cvtpk(float lo, float hi) {
  unsigned int r;
  asm("v_cvt_pk_bf16_f32 %0, %1, %2" : "=v"(r) : "v"(lo), "v"(hi));
  return r;
}
__device__ __forceinline__ f32x16 zero16() {
  f32x16 z;
#pragma unroll
  for (int i = 0; i < 16; ++i) z[i] = 0.f;
  return z;
}

// ---------------- prep: WB[j][k][d][i] = bf16(W[k][j][d][i]);  XT[j][b][i] = bf16(x[b][j][i])
__global__ __launch_bounds__(256) void k_prep(const float* __restrict__ inp,
                                              const float* __restrict__ W,
                                              unsigned short* __restrict__ WB,
                                              unsigned short* __restrict__ XT) {
  const size_t tid = (size_t)blockIdx.x * 256 + threadIdx.x;
  const size_t stride = (size_t)gridDim.x * 256;
  for (size_t g8 = tid; g8 < (size_t)J_ * K_ * 32; g8 += stride) {
    const size_t o = g8 * 8;
    const int j = (int)(o >> 13), k = (int)((o >> 8) & 31), di = (int)(o & 255);
    const float* src = W + ((size_t)k * J_ + j) * 256 + di;
    const float4 a = *(const float4*)src;
    const float4 b = *(const float4*)(src + 4);
    uint4 pk;
    pk.x = cvtpk(a.x, a.y);
    pk.y = cvtpk(a.z, a.w);
    pk.z = cvtpk(b.x, b.y);
    pk.w = cvtpk(b.z, b.w);
    *(uint4*)(WB + o) = pk;
  }
  for (size_t g8 = tid; g8 < (size_t)J_ * B_ * 2; g8 += stride) {
    const size_t o = g8 * 8;
    const int j = (int)(o >> 10), b = (int)((o >> 4) & 63), i0 = (int)(o & 15);
    const float* src = inp + ((size_t)b * J_ + j) * 16 + i0;
    const float4 a = *(const float4*)src;
    const float4 c = *(const float4*)(src + 4);
    uint4 pk;
    pk.x = cvtpk(a.x, a.y);
    pk.y = cvtpk(a.z, a.w);
    pk.z = cvtpk(c.x, c.y);
    pk.w = cvtpk(c.z, c.w);
    *(uint4*)(XT + o) = pk;
  }
}

// ---------------- k_R: one fused routing sweep. u computed ONCE via 32x32 MFMA and
// consumed from registers for both the logit dot and the s-accumulation.
// Grid 256 (1 block/CU), 512 threads = 8 waves: wave = (kq = w&3, bt = w>>2).
// Wave covers k in [8kq, 8kq+8) x 32 b (b = bt*32 + lane&31), 8 j's.
// Lane (hi, b31): per k-pair tp, u regs 0-7 = k-even d=(s&3)+4hi+8(s>>2), 8-15 = k-odd.
// Softmax: in-lane dot + shfl_xor(32) -> partial S per wave -> LDS cross-wave sum
// (1 barrier/j, double-buffered). MODE 0: c=1/32, no softmax/barriers.
// MODE 2: also writes cT[j][k][b] (final c for output).
template <int MODE>
__global__ __launch_bounds__(512, 2) void k_R(const unsigned short* __restrict__ XT,
                                              const unsigned short* __restrict__ WB,
                                              const unsigned short* __restrict__ osB,
                                              float* __restrict__ spart,
                                              float* __restrict__ cT) {
  const int ch = blockIdx.x;
  const int t = threadIdx.x;
  const int wave = t >> 6, lane = t & 63;
  const int kq = wave & 3, bt = wave >> 2;
  const int hi = lane >> 5, b31 = lane & 31;
  const int b = bt * 32 + b31;
  const int j0 = ch * JCR;

  __shared__ float Sbuf[(MODE >= 1) ? 2 * 4 * 2 * 32 : 4];

  // hoisted packed os for k = 8kq .. 8kq+7 (slot s <-> d = (s&3)+4hi+8*(s>>2))
  uint4 os_pk[8];
  if constexpr (MODE >= 1) {
    const unsigned short* osb = osB + ((size_t)bt * 64 + lane) * 8 + (size_t)(8 * kq) * 1024;
#pragma unroll
    for (int kk = 0; kk < 8; ++kk) os_pk[kk] = *(const uint4*)(osb + (size_t)kk * 1024);
  }

  float acc[4][16];
#pragma unroll
  for (int q = 0; q < 4; ++q)
#pragma unroll
    for (int s = 0; s < 16; ++s) acc[q][s] = 0.f;

  // A-frag base: lane's A-row = b31 -> (k-parity = b31>>4, d = b31&15); i-slots = 8hi..
  const unsigned short* waBase =
      WB + (size_t)j0 * 8192 + (b31 >> 4) * 256 + (b31 & 15) * 16 + 8 * hi + (size_t)kq * 2048;
  const unsigned short* xBase = XT + (size_t)j0 * 1024 + b * 16 + 8 * hi;

  uint4 a_cur[4], b_cur;
#pragma unroll
  for (int q = 0; q < 4; ++q) a_cur[q] = *(const uint4*)(waBase + q * 512);
  b_cur = *(const uint4*)(xBase);

  for (int jj = 0; jj < JCR; ++jj) {
    // prefetch next j's fragments (independent of everything below)
    uint4 a_nxt[4], b_nxt;
    if (jj + 1 < JCR) {
#pragma unroll
      for (int q = 0; q < 4; ++q)
        a_nxt[q] = *(const uint4*)(waBase + (size_t)(jj + 1) * 8192 + q * 512);
      b_nxt = *(const uint4*)(xBase + (size_t)(jj + 1) * 1024);
    }

    f32x16 u[4];
#pragma unroll
    for (int q = 0; q < 4; ++q)
      u[q] = __builtin_amdgcn_mfma_f32_32x32x16_bf16(
          __builtin_bit_cast(short8v, a_cur[q]), __builtin_bit_cast(short8v, b_cur),
          zero16(), 0, 0, 0);

    if constexpr (MODE == 0) {
#pragma unroll
      for (int q = 0; q < 4; ++q)
#pragma unroll
        for (int s = 0; s < 16; ++s) acc[q][s] += u[q][s];
    } else {
      float ee[4], eo[4];
      float Sp = 0.f;
#pragma unroll
      for (int q = 0; q < 4; ++q) {
        const unsigned int* o0 = (const unsigned int*)&os_pk[2 * q];
        const unsigned int* o1 = (const unsigned int*)&os_pk[2 * q + 1];
        float pe = 0.f, po = 0.f;
#pragma unroll
        for (int s = 0; s < 8; ++s) {
          const unsigned int w0 = o0[s >> 1], w1 = o1[s >> 1];
          pe = fmaf(u[q][s], bf2f((s & 1) ? (w0 >> 16) : (w0 & 0xffffu)), pe);
          po = fmaf(u[q][8 + s], bf2f((s & 1) ? (w1 >> 16) : (w1 & 0xffffu)), po);
        }
        pe += __shfl_xor(pe, 32);      // partner hi-half -> full dot over d
        po += __shfl_xor(po, 32);
        // logits O(+-8): skip max-subtraction (shift-invariant; validated r1-r13)
        ee[q] = __expf(pe);
        eo[q] = __expf(po);
        Sp += ee[q] + eo[q];
      }
      // cross-wave S reduction over the 4 kq waves (same bt)
      if (hi == 0) Sbuf[((jj & 1) * 8 + kq * 2 + bt) * 32 + b31] = Sp;
      __syncthreads();
      const int sb = (jj & 1) * 8;
      const float S = Sbuf[(sb + 0 * 2 + bt) * 32 + b31] + Sbuf[(sb + 1 * 2 + bt) * 32 + b31] +
                      Sbuf[(sb + 2 * 2 + bt) * 32 + b31] + Sbuf[(sb + 3 * 2 + bt) * 32 + b31];
      const float rS = __builtin_amdgcn_rcpf(S);
#pragma unroll
      for (int q = 0; q < 4; ++q) {
        const float ce = ee[q] * rS, co = eo[q] * rS;
#pragma unroll
        for (int s = 0; s < 8; ++s) {
          acc[q][s] = fmaf(ce, u[q][s], acc[q][s]);
          acc[q][8 + s] = fmaf(co, u[q][8 + s], acc[q][8 + s]);
        }
        if constexpr (MODE == 2) {
          if (hi == 0) {
            const int k0 = 8 * kq + 2 * q;
            cT[(size_t)(j0 + jj) * 2048 + (size_t)k0 * 64 + b] = ce;        // coalesced
            cT[(size_t)(j0 + jj) * 2048 + (size_t)(k0 + 1) * 64 + b] = co;
          }
        }
      }
    }
#pragma unroll
    for (int q = 0; q < 4; ++q) a_cur[q] = a_nxt[q];
    b_cur = b_nxt;
  }

  // ---- spart store: per (q, parity) the 8 d's form two contiguous float4 runs
  const float sc = (MODE == 0) ? (1.f / 32.f) : 1.f;
#pragma unroll
  for (int q = 0; q < 4; ++q) {
    const int keven = 8 * kq + 2 * q;
    float* se = spart + (((size_t)b * NCH + ch) * 32 + keven) * 16 + 4 * hi;
    *(float4*)se = make_float4(acc[q][0] * sc, acc[q][1] * sc, acc[q][2] * sc, acc[q][3] * sc);
    *(float4*)(se + 8) =
        make_float4(acc[q][4] * sc, acc[q][5] * sc, acc[q][6] * sc, acc[q][7] * sc);
    float* so = se + 16;   // k odd
    *(float4*)so =
        make_float4(acc[q][8] * sc, acc[q][9] * sc, acc[q][10] * sc, acc[q][11] * sc);
    *(float4*)(so + 8) =
        make_float4(acc[q][12] * sc, acc[q][13] * sc, acc[q][14] * sc, acc[q][15] * sc);
  }
}

// ---------------- k_cout: cT[j][k][b] -> outp[b][k][16+j], block = (k, j-chunk of 128).
__global__ __launch_bounds__(256) void k_cout(const float* __restrict__ cT,
                                              float* __restrict__ outp) {
  const int k = blockIdx.x & 31, j0 = (blockIdx.x >> 5) * 128;
  const int t = threadIdx.x;
  __shared__ float lds[64][129];
#pragma unroll
  for (int m = 0; m < 32; ++m) {
    const int jj = m * 4 + (t >> 6), b = t & 63;
    lds[b][jj] = cT[((size_t)(j0 + jj) * 32 + k) * 64 + b];   // coalesced 256B
  }
  __syncthreads();
#pragma unroll
  for (int m = 0; m < 8; ++m) {
    const int b = m * 8 + (t >> 5), jq = (t & 31) * 4;
    *(float4*)(outp + ((size_t)b * 32 + k) * 2064 + 16 + j0 + jq) =
        make_float4(lds[b][jq], lds[b][jq + 1], lds[b][jq + 2], lds[b][jq + 3]);
  }
}

// ---------------- squash: reduce spart (depth NCH) -> s, squash -> o; f32 osum master +
// bf16 osB mirror in k_R's fragment layout [k][bt][hi*32+b31][slot].
__global__ __launch_bounds__(256) void k_squash(const float* __restrict__ spart,
                                                float* __restrict__ osum,
                                                unsigned short* __restrict__ osB,
                                                float* __restrict__ outp,
                                                int first, int final_) {
  const int t = threadIdx.x;
  const int wave = t >> 6, lane = t & 63;
  const int gw = blockIdx.x * 4 + wave;   // 0..B_*K_-1
  const int b = gw >> 5, k = gw & 31;
  const int d = lane & 15, pg = lane >> 4;
  float s = 0.f;
#pragma unroll 8
  for (int p = pg; p < NCH; p += 4)
    s += spart[(((size_t)b * NCH + p) * 32 + k) * 16 + d];
  s += __shfl_xor(s, 16);
  s += __shfl_xor(s, 32);
  float ss = s * s;
  ss += __shfl_xor(ss, 1); ss += __shfl_xor(ss, 2);
  ss += __shfl_xor(ss, 4); ss += __shfl_xor(ss, 8);
  const float scale = (ss / (1.f + ss)) * rsqrtf(ss + 1e-7f);
  const float ov = scale * s;
  if (final_) {
    if (lane < 16) outp[((size_t)b * K_ + k) * 2064 + d] = ov;
  } else {
    const float prev = first ? 0.f : osum[b * KD + k * 16 + d];
    const float ns = prev + ov;
    if (lane < 16) {
      osum[b * KD + k * 16 + d] = ns;
      // osB scatter: d -> (hi, slot): hi = (d>>2)&1, slot = (d&3) + 4*(d>>3)
      const int hi = (d >> 2) & 1;
      const int slot = (d & 3) + ((d >> 3) << 2);
      osB[(((size_t)k * 2 + (b >> 5)) * 64 + hi * 32 + (b & 31)) * 8 + slot] = f2bf(ns);
    }
  }
}

extern "C" void kernel_launch(void* const* d_in, const int* in_sizes, int n_in,
                              void* d_out, int out_size, void* d_ws, size_t ws_size,
                              hipStream_t stream) {
  const float* inp = (const float*)d_in[0];   // [64,2048,16]
  const float* W   = (const float*)d_in[1];   // [32,2048,16,16]
  float* outp = (float*)d_out;                // [64,32,2064]
  char* ws = (char*)d_ws;
  // ws: WB 32M @0 | XT 4M @32M | cT 16M @36M | spart 32M @52M | osum 128K @84M | osB 64K
  unsigned short* WB = (unsigned short*)ws;
  unsigned short* XT = (unsigned short*)(ws + (size_t)33554432);
  float* cT    = (float*)(ws + (size_t)37748736);
  float* spart = (float*)(ws + (size_t)54525952);
  float* osum  = (float*)(ws + (size_t)88080384);
  unsigned short* osB = (unsigned short*)(ws + (size_t)88211456);

  k_prep<<<2048, 256, 0, stream>>>(inp, W, WB, XT);
  // iter 0: c = 1/32
  k_R<0><<<NCH, 512, 0, stream>>>(XT, WB, nullptr, spart, nullptr);
  k_squash<<<B_ * K_ / 4, 256, 0, stream>>>(spart, osum, osB, outp, 1, 0);
  // iter 1
  k_R<1><<<NCH, 512, 0, stream>>>(XT, WB, osB, spart, nullptr);
  k_squash<<<B_ * K_ / 4, 256, 0, stream>>>(spart, osum, osB, outp, 0, 0);
  // iter 2 (final): k_R<2> also emits c -> cT
  k_R<2><<<NCH, 512, 0, stream>>>(XT, WB, osB, spart, cT);
  k_squash<<<B_ * K_ / 4, 256, 0, stream>>>(spart, osum, osB, outp, 0, 1);
  k_cout<<<K_ * 16, 256, 0, stream>>>(cT, outp);
}

// Round 15
// 95.552 us; speedup vs baseline: 1.2698x; 1.1035x over previous
//
#include <hip/hip_runtime.h>
#include <hip/hip_bf16.h>

#define B_ 64
#define J_ 2048
#define K_ 32
#define D_ 16
#define KD 512
#define NCH 256      // j-chunks (spart partial depth)
#define JCR 8        // j's per k_R block

typedef __attribute__((ext_vector_type(8))) short short8v;    // 8 bf16 (4 VGPR)
typedef __attribute__((ext_vector_type(16))) float f32x16;    // 16 f32 acc (32x32)

__device__ __forceinline__ float bf2f(unsigned int bits16) {
  unsigned int u = bits16 << 16;
  return __builtin_bit_cast(float, u);
}
__device__ __forceinline__ unsigned int f2bf(float f) {
  unsigned int u = __builtin_bit_cast(unsigned int, f);
  u = u + 0x7fffu + ((u >> 16) & 1u);   // round-to-nearest-even
  return u >> 16;
}
// HW packed f32->bf16 pair convert (gfx950; no builtin -- inline asm). lo -> low16.
__device__ __forceinline__ unsigned int cvtpk(float lo, float hi) {
  unsigned int r;
  asm("v_cvt_pk_bf16_f32 %0, %1, %2" : "=v"(r) : "v"(lo), "v"(hi));
  return r;
}
__device__ __forceinline__ f32x16 zero16() {
  f32x16 z;
#pragma unroll
  for (int i = 0; i < 16; ++i) z[i] = 0.f;
  return z;
}

// ---------------- prep: WB[j][k][d][i] = bf16(W[k][j][d][i]);  XT[j][b][i] = bf16(x[b][j][i])
__global__ __launch_bounds__(256) void k_prep(const float* __restrict__ inp,
                                              const float* __restrict__ W,
                                              unsigned short* __restrict__ WB,
                                              unsigned short* __restrict__ XT) {
  const size_t tid = (size_t)blockIdx.x * 256 + threadIdx.x;
  const size_t stride = (size_t)gridDim.x * 256;
  for (size_t g8 = tid; g8 < (size_t)J_ * K_ * 32; g8 += stride) {
    const size_t o = g8 * 8;
    const int j = (int)(o >> 13), k = (int)((o >> 8) & 31), di = (int)(o & 255);
    const float* src = W + ((size_t)k * J_ + j) * 256 + di;
    const float4 a = *(const float4*)src;
    const float4 b = *(const float4*)(src + 4);
    uint4 pk;
    pk.x = cvtpk(a.x, a.y);
    pk.y = cvtpk(a.z, a.w);
    pk.z = cvtpk(b.x, b.y);
    pk.w = cvtpk(b.z, b.w);
    *(uint4*)(WB + o) = pk;
  }
  for (size_t g8 = tid; g8 < (size_t)J_ * B_ * 2; g8 += stride) {
    const size_t o = g8 * 8;
    const int j = (int)(o >> 10), b = (int)((o >> 4) & 63), i0 = (int)(o & 15);
    const float* src = inp + ((size_t)b * J_ + j) * 16 + i0;
    const float4 a = *(const float4*)src;
    const float4 c = *(const float4*)(src + 4);
    uint4 pk;
    pk.x = cvtpk(a.x, a.y);
    pk.y = cvtpk(a.z, a.w);
    pk.z = cvtpk(c.x, c.y);
    pk.w = cvtpk(c.z, c.w);
    *(uint4*)(XT + o) = pk;
  }
}

// ---------------- k_R: one fused routing sweep (r14-proven). u via 32x32 MFMA, consumed
// from registers for logit dot AND s-accumulation. Grid 256, 512 thr = 8 waves (kq, bt).
// NEW r15: s-partials stored bf16-packed (d-pairs via v_cvt_pk_bf16_f32) -> 16MB/sweep.
// MODE 0: c=1/32, no softmax/barriers. MODE 2: also writes cT[j][k][b] (final c).
template <int MODE>
__global__ __launch_bounds__(512, 2) void k_R(const unsigned short* __restrict__ XT,
                                              const unsigned short* __restrict__ WB,
                                              const unsigned short* __restrict__ osB,
                                              unsigned int* __restrict__ spart_pk,
                                              float* __restrict__ cT) {
  const int ch = blockIdx.x;
  const int t = threadIdx.x;
  const int wave = t >> 6, lane = t & 63;
  const int kq = wave & 3, bt = wave >> 2;
  const int hi = lane >> 5, b31 = lane & 31;
  const int b = bt * 32 + b31;
  const int j0 = ch * JCR;

  __shared__ float Sbuf[(MODE >= 1) ? 2 * 4 * 2 * 32 : 4];

  // hoisted packed os for k = 8kq .. 8kq+7 (slot s <-> d = (s&3)+4hi+8*(s>>2))
  uint4 os_pk[8];
  if constexpr (MODE >= 1) {
    const unsigned short* osb = osB + ((size_t)bt * 64 + lane) * 8 + (size_t)(8 * kq) * 1024;
#pragma unroll
    for (int kk = 0; kk < 8; ++kk) os_pk[kk] = *(const uint4*)(osb + (size_t)kk * 1024);
  }

  float acc[4][16];
#pragma unroll
  for (int q = 0; q < 4; ++q)
#pragma unroll
    for (int s = 0; s < 16; ++s) acc[q][s] = 0.f;

  // A-frag base: lane's A-row = b31 -> (k-parity = b31>>4, d = b31&15); i-slots = 8hi..
  const unsigned short* waBase =
      WB + (size_t)j0 * 8192 + (b31 >> 4) * 256 + (b31 & 15) * 16 + 8 * hi + (size_t)kq * 2048;
  const unsigned short* xBase = XT + (size_t)j0 * 1024 + b * 16 + 8 * hi;

  uint4 a_cur[4], b_cur;
#pragma unroll
  for (int q = 0; q < 4; ++q) a_cur[q] = *(const uint4*)(waBase + q * 512);
  b_cur = *(const uint4*)(xBase);

  for (int jj = 0; jj < JCR; ++jj) {
    // prefetch next j's fragments (independent of everything below)
    uint4 a_nxt[4], b_nxt;
    if (jj + 1 < JCR) {
#pragma unroll
      for (int q = 0; q < 4; ++q)
        a_nxt[q] = *(const uint4*)(waBase + (size_t)(jj + 1) * 8192 + q * 512);
      b_nxt = *(const uint4*)(xBase + (size_t)(jj + 1) * 1024);
    }

    f32x16 u[4];
#pragma unroll
    for (int q = 0; q < 4; ++q)
      u[q] = __builtin_amdgcn_mfma_f32_32x32x16_bf16(
          __builtin_bit_cast(short8v, a_cur[q]), __builtin_bit_cast(short8v, b_cur),
          zero16(), 0, 0, 0);

    if constexpr (MODE == 0) {
#pragma unroll
      for (int q = 0; q < 4; ++q)
#pragma unroll
        for (int s = 0; s < 16; ++s) acc[q][s] += u[q][s];
    } else {
      float ee[4], eo[4];
      float Sp = 0.f;
#pragma unroll
      for (int q = 0; q < 4; ++q) {
        const unsigned int* o0 = (const unsigned int*)&os_pk[2 * q];
        const unsigned int* o1 = (const unsigned int*)&os_pk[2 * q + 1];
        float pe = 0.f, po = 0.f;
#pragma unroll
        for (int s = 0; s < 8; ++s) {
          const unsigned int w0 = o0[s >> 1], w1 = o1[s >> 1];
          pe = fmaf(u[q][s], bf2f((s & 1) ? (w0 >> 16) : (w0 & 0xffffu)), pe);
          po = fmaf(u[q][8 + s], bf2f((s & 1) ? (w1 >> 16) : (w1 & 0xffffu)), po);
        }
        pe += __shfl_xor(pe, 32);      // partner hi-half -> full dot over d
        po += __shfl_xor(po, 32);
        // logits O(+-8): skip max-subtraction (shift-invariant; validated r1-r14)
        ee[q] = __expf(pe);
        eo[q] = __expf(po);
        Sp += ee[q] + eo[q];
      }
      // cross-wave S reduction over the 4 kq waves (same bt)
      if (hi == 0) Sbuf[((jj & 1) * 8 + kq * 2 + bt) * 32 + b31] = Sp;
      __syncthreads();
      const int sb = (jj & 1) * 8;
      const float S = Sbuf[(sb + 0 * 2 + bt) * 32 + b31] + Sbuf[(sb + 1 * 2 + bt) * 32 + b31] +
                      Sbuf[(sb + 2 * 2 + bt) * 32 + b31] + Sbuf[(sb + 3 * 2 + bt) * 32 + b31];
      const float rS = __builtin_amdgcn_rcpf(S);
#pragma unroll
      for (int q = 0; q < 4; ++q) {
        const float ce = ee[q] * rS, co = eo[q] * rS;
#pragma unroll
        for (int s = 0; s < 8; ++s) {
          acc[q][s] = fmaf(ce, u[q][s], acc[q][s]);
          acc[q][8 + s] = fmaf(co, u[q][8 + s], acc[q][8 + s]);
        }
        if constexpr (MODE == 2) {
          if (hi == 0) {
            const int k0 = 8 * kq + 2 * q;
            cT[(size_t)(j0 + jj) * 2048 + (size_t)k0 * 64 + b] = ce;        // coalesced
            cT[(size_t)(j0 + jj) * 2048 + (size_t)(k0 + 1) * 64 + b] = co;
          }
        }
      }
    }
#pragma unroll
    for (int q = 0; q < 4; ++q) a_cur[q] = a_nxt[q];
    b_cur = b_nxt;
  }

  // ---- spart store, bf16-packed d-pairs. Lane covers d = {4hi..4hi+3, 8+4hi..8+4hi+3}
  // -> d-pair indices {2hi, 2hi+1} and {4+2hi, 4+2hi+1} per k.
  const float sc = (MODE == 0) ? (1.f / 32.f) : 1.f;
#pragma unroll
  for (int q = 0; q < 4; ++q) {
    const int keven = 8 * kq + 2 * q;
    unsigned int* se = spart_pk + (((size_t)b * NCH + ch) * 32 + keven) * 8 + 2 * hi;
    *(uint2*)se = make_uint2(cvtpk(acc[q][0] * sc, acc[q][1] * sc),
                             cvtpk(acc[q][2] * sc, acc[q][3] * sc));
    *(uint2*)(se + 4) = make_uint2(cvtpk(acc[q][4] * sc, acc[q][5] * sc),
                                   cvtpk(acc[q][6] * sc, acc[q][7] * sc));
    unsigned int* so = se + 8;   // k odd
    *(uint2*)so = make_uint2(cvtpk(acc[q][8] * sc, acc[q][9] * sc),
                             cvtpk(acc[q][10] * sc, acc[q][11] * sc));
    *(uint2*)(so + 4) = make_uint2(cvtpk(acc[q][12] * sc, acc[q][13] * sc),
                                   cvtpk(acc[q][14] * sc, acc[q][15] * sc));
  }
}

// ---------------- k_cout: cT[j][k][b] -> outp[b][k][16+j], block = (k, j-chunk of 128).
__global__ __launch_bounds__(256) void k_cout(const float* __restrict__ cT,
                                              float* __restrict__ outp) {
  const int k = blockIdx.x & 31, j0 = (blockIdx.x >> 5) * 128;
  const int t = threadIdx.x;
  __shared__ float lds[64][129];
#pragma unroll
  for (int m = 0; m < 32; ++m) {
    const int jj = m * 4 + (t >> 6), b = t & 63;
    lds[b][jj] = cT[((size_t)(j0 + jj) * 32 + k) * 64 + b];   // coalesced 256B
  }
  __syncthreads();
#pragma unroll
  for (int m = 0; m < 8; ++m) {
    const int b = m * 8 + (t >> 5), jq = (t & 31) * 4;
    *(float4*)(outp + ((size_t)b * 32 + k) * 2064 + 16 + j0 + jq) =
        make_float4(lds[b][jq], lds[b][jq + 1], lds[b][jq + 2], lds[b][jq + 3]);
  }
}

// ---------------- squash: reduce packed spart (depth NCH) -> s, squash -> o.
// Wave per (b,k). Lane: h = d-pair (d = 2h, 2h+1), pg = lane>>3 (8 p-groups).
// f32 osum master + bf16 osB mirror (packed store: consecutive d -> consecutive slot).
__global__ __launch_bounds__(256) void k_squash(const unsigned int* __restrict__ spart_pk,
                                                float* __restrict__ osum,
                                                unsigned short* __restrict__ osB,
                                                float* __restrict__ outp,
                                                int first, int final_) {
  const int t = threadIdx.x;
  const int wave = t >> 6, lane = t & 63;
  const int gw = blockIdx.x * 4 + wave;   // 0..B_*K_-1
  const int b = gw >> 5, k = gw & 31;
  const int h = lane & 7, pg = lane >> 3;
  float s0 = 0.f, s1 = 0.f;
#pragma unroll 8
  for (int p = pg; p < NCH; p += 8) {
    const unsigned int v = spart_pk[(((size_t)b * NCH + p) * 32 + k) * 8 + h];
    s0 += bf2f(v & 0xffffu);
    s1 += bf2f(v >> 16);
  }
  s0 += __shfl_xor(s0, 8);  s1 += __shfl_xor(s1, 8);
  s0 += __shfl_xor(s0, 16); s1 += __shfl_xor(s1, 16);
  s0 += __shfl_xor(s0, 32); s1 += __shfl_xor(s1, 32);
  float ss = s0 * s0 + s1 * s1;
  ss += __shfl_xor(ss, 1); ss += __shfl_xor(ss, 2); ss += __shfl_xor(ss, 4);
  const float scale = (ss / (1.f + ss)) * rsqrtf(ss + 1e-7f);
  const float ov0 = scale * s0, ov1 = scale * s1;
  if (final_) {
    if (pg == 0)
      *(float2*)(outp + ((size_t)b * K_ + k) * 2064 + 2 * h) = make_float2(ov0, ov1);
  } else {
    if (pg == 0) {
      float2 prev = make_float2(0.f, 0.f);
      if (!first) prev = *(const float2*)(osum + b * KD + k * 16 + 2 * h);
      const float ns0 = prev.x + ov0, ns1 = prev.y + ov1;
      *(float2*)(osum + b * KD + k * 16 + 2 * h) = make_float2(ns0, ns1);
      // osB: d0 = 2h (even) -> hi0 = (d0>>2)&1, slot0 = (d0&3)+((d0>>3)<<2); d1 = slot0+1
      const int d0 = 2 * h;
      const int hi0 = (d0 >> 2) & 1;
      const int slot0 = (d0 & 3) + ((d0 >> 3) << 2);
      *(unsigned int*)(osB + (((size_t)k * 2 + (b >> 5)) * 64 + hi0 * 32 + (b & 31)) * 8 +
                       slot0) = cvtpk(ns0, ns1);
    }
  }
}

extern "C" void kernel_launch(void* const* d_in, const int* in_sizes, int n_in,
                              void* d_out, int out_size, void* d_ws, size_t ws_size,
                              hipStream_t stream) {
  const float* inp = (const float*)d_in[0];   // [64,2048,16]
  const float* W   = (const float*)d_in[1];   // [32,2048,16,16]
  float* outp = (float*)d_out;                // [64,32,2064]
  char* ws = (char*)d_ws;
  // ws: WB 32M @0 | XT 4M @32M | cT 16M @36M | spart_pk 16M @52M | osum 128K @84M | osB 64K
  unsigned short* WB = (unsigned short*)ws;
  unsigned short* XT = (unsigned short*)(ws + (size_t)33554432);
  float* cT    = (float*)(ws + (size_t)37748736);
  unsigned int* spart_pk = (unsigned int*)(ws + (size_t)54525952);
  float* osum  = (float*)(ws + (size_t)88080384);
  unsigned short* osB = (unsigned short*)(ws + (size_t)88211456);

  k_prep<<<2048, 256, 0, stream>>>(inp, W, WB, XT);
  // iter 0: c = 1/32
  k_R<0><<<NCH, 512, 0, stream>>>(XT, WB, nullptr, spart_pk, nullptr);
  k_squash<<<B_ * K_ / 4, 256, 0, stream>>>(spart_pk, osum, osB, outp, 1, 0);
  // iter 1
  k_R<1><<<NCH, 512, 0, stream>>>(XT, WB, osB, spart_pk, nullptr);
  k_squash<<<B_ * K_ / 4, 256, 0, stream>>>(spart_pk, osum, osB, outp, 0, 0);
  // iter 2 (final): k_R<2> also emits c -> cT
  k_R<2><<<NCH, 512, 0, stream>>>(XT, WB, osB, spart_pk, cT);
  k_squash<<<B_ * K_ / 4, 256, 0, stream>>>(spart_pk, osum, osB, outp, 0, 1);
  k_cout<<<K_ * 16, 256, 0, stream>>>(cT, outp);
}

// Round 16
// 93.493 us; speedup vs baseline: 1.2977x; 1.0220x over previous
//
#include <hip/hip_runtime.h>
#include <hip/hip_bf16.h>

#define B_ 64
#define J_ 2048
#define K_ 32
#define D_ 16
#define KD 512
#define NCH 256      // j-chunks (spart partial depth) == grid of k_R
#define JCR 8        // j's per k_R block

typedef __attribute__((ext_vector_type(8))) short short8v;    // 8 bf16 (4 VGPR)
typedef __attribute__((ext_vector_type(16))) float f32x16;    // 16 f32 acc (32x32)

__device__ __forceinline__ float bf2f(unsigned int bits16) {
  unsigned int u = bits16 << 16;
  return __builtin_bit_cast(float, u);
}
__device__ __forceinline__ unsigned int f2bf(float f) {
  unsigned int u = __builtin_bit_cast(unsigned int, f);
  u = u + 0x7fffu + ((u >> 16) & 1u);   // round-to-nearest-even
  return u >> 16;
}
// HW packed f32->bf16 pair convert (gfx950; no builtin -- inline asm). lo -> low16.
__device__ __forceinline__ unsigned int cvtpk(float lo, float hi) {
  unsigned int r;
  asm("v_cvt_pk_bf16_f32 %0, %1, %2" : "=v"(r) : "v"(lo), "v"(hi));
  return r;
}
__device__ __forceinline__ f32x16 zero16() {
  f32x16 z;
#pragma unroll
  for (int i = 0; i < 16; ++i) z[i] = 0.f;
  return z;
}

// ---------------- prepX: XT[j][b][i] = bf16(x[b][j][i])  (x only; W handled in k_R0W)
__global__ __launch_bounds__(256) void k_prepX(const float* __restrict__ inp,
                                               unsigned short* __restrict__ XT) {
  const size_t tid = (size_t)blockIdx.x * 256 + threadIdx.x;
  const size_t stride = (size_t)gridDim.x * 256;
  for (size_t g8 = tid; g8 < (size_t)J_ * B_ * 2; g8 += stride) {
    const size_t o = g8 * 8;
    const int j = (int)(o >> 10), b = (int)((o >> 4) & 63), i0 = (int)(o & 15);
    const float* src = inp + ((size_t)b * J_ + j) * 16 + i0;
    const float4 a = *(const float4*)src;
    const float4 c = *(const float4*)(src + 4);
    uint4 pk;
    pk.x = cvtpk(a.x, a.y);
    pk.y = cvtpk(a.z, a.w);
    pk.z = cvtpk(c.x, c.y);
    pk.w = cvtpk(c.z, c.w);
    *(uint4*)(XT + o) = pk;
  }
}

// ---------------- k_R0W: iter-0 sweep (c = 1/32) FUSED with W f32->bf16 conversion.
// Lane's W f32 loads ARE the A-fragment rows (wave covers contiguous 1KB per k);
// converted uint4 doubles as the WB store (bt==0 waves only). MFMA accumulates via
// C-in. Depth-1 jj prefetch (r15-proven): 8 float4/wave in flight = HBM-saturating.
__global__ __launch_bounds__(512, 2) void k_R0W(const float* __restrict__ W,
                                                const unsigned short* __restrict__ XT,
                                                unsigned short* __restrict__ WB,
                                                unsigned int* __restrict__ spart_pk) {
  const int ch = blockIdx.x;
  const int t = threadIdx.x;
  const int wave = t >> 6, lane = t & 63;
  const int kq = wave & 3, bt = wave >> 2;
  const int hi = lane >> 5, b31 = lane & 31;
  const int b = bt * 32 + b31;
  const int j0 = ch * JCR;

  // lane's W row: k(q) = 8kq + 2q + (b31>>4), d = b31&15, i0 = 8hi
  const float* wsrc = W + ((size_t)(8 * kq + (b31 >> 4)) * J_ + j0) * 256 +
                      (b31 & 15) * 16 + 8 * hi;             // + q*qstep + jj*256
  unsigned short* wdst = WB + (size_t)j0 * 8192 + kq * 2048 + (b31 >> 4) * 256 +
                         (b31 & 15) * 16 + 8 * hi;          // + q*512 + jj*8192
  const unsigned short* xBase = XT + (size_t)j0 * 1024 + b * 16 + 8 * hi;
  const size_t qstep = (size_t)2 * J_ * 256;                // f32 elems between q k-pairs

  f32x16 acc[4];
#pragma unroll
  for (int q = 0; q < 4; ++q) acc[q] = zero16();

  float4 wc[8];
  uint4 xc;
#pragma unroll
  for (int q = 0; q < 4; ++q) {
    wc[2 * q]     = *(const float4*)(wsrc + (size_t)q * qstep);
    wc[2 * q + 1] = *(const float4*)(wsrc + (size_t)q * qstep + 4);
  }
  xc = *(const uint4*)xBase;

  for (int jj = 0; jj < JCR; ++jj) {
    float4 wn[8];
    uint4 xn;
    if (jj + 1 < JCR) {
#pragma unroll
      for (int q = 0; q < 4; ++q) {
        const float* ws2 = wsrc + (size_t)(jj + 1) * 256 + (size_t)q * qstep;
        wn[2 * q] = *(const float4*)ws2;
        wn[2 * q + 1] = *(const float4*)(ws2 + 4);
      }
      xn = *(const uint4*)(xBase + (size_t)(jj + 1) * 1024);
    }
    const short8v xf = __builtin_bit_cast(short8v, xc);
#pragma unroll
    for (int q = 0; q < 4; ++q) {
      uint4 wv;
      wv.x = cvtpk(wc[2 * q].x, wc[2 * q].y);
      wv.y = cvtpk(wc[2 * q].z, wc[2 * q].w);
      wv.z = cvtpk(wc[2 * q + 1].x, wc[2 * q + 1].y);
      wv.w = cvtpk(wc[2 * q + 1].z, wc[2 * q + 1].w);
      if (bt == 0) *(uint4*)(wdst + (size_t)jj * 8192 + q * 512) = wv;  // WB side-product
      acc[q] = __builtin_amdgcn_mfma_f32_32x32x16_bf16(
          __builtin_bit_cast(short8v, wv), xf, acc[q], 0, 0, 0);
    }
#pragma unroll
    for (int p = 0; p < 8; ++p) wc[p] = wn[p];
    xc = xn;
  }

  // spart store, bf16-packed d-pairs (r15 layout), sc = 1/32
  const float sc = 1.f / 32.f;
#pragma unroll
  for (int q = 0; q < 4; ++q) {
    const int keven = 8 * kq + 2 * q;
    unsigned int* se = spart_pk + (((size_t)b * NCH + ch) * 32 + keven) * 8 + 2 * hi;
    *(uint2*)se = make_uint2(cvtpk(acc[q][0] * sc, acc[q][1] * sc),
                             cvtpk(acc[q][2] * sc, acc[q][3] * sc));
    *(uint2*)(se + 4) = make_uint2(cvtpk(acc[q][4] * sc, acc[q][5] * sc),
                                   cvtpk(acc[q][6] * sc, acc[q][7] * sc));
    unsigned int* so = se + 8;
    *(uint2*)so = make_uint2(cvtpk(acc[q][8] * sc, acc[q][9] * sc),
                             cvtpk(acc[q][10] * sc, acc[q][11] * sc));
    *(uint2*)(so + 4) = make_uint2(cvtpk(acc[q][12] * sc, acc[q][13] * sc),
                                   cvtpk(acc[q][14] * sc, acc[q][15] * sc));
  }
}

// ---------------- k_R: fused routing sweep (r15-proven). MODE 1: plain. MODE 2: final
// iteration -- c written to padded LDS tile and transposed directly into outp (no cT).
template <int MODE>
__global__ __launch_bounds__(512, 2) void k_R(const unsigned short* __restrict__ XT,
                                              const unsigned short* __restrict__ WB,
                                              const unsigned short* __restrict__ osB,
                                              unsigned int* __restrict__ spart_pk,
                                              float* __restrict__ outp) {
  const int ch = blockIdx.x;
  const int t = threadIdx.x;
  const int wave = t >> 6, lane = t & 63;
  const int kq = wave & 3, bt = wave >> 2;
  const int hi = lane >> 5, b31 = lane & 31;
  const int b = bt * 32 + b31;
  const int j0 = ch * JCR;

  __shared__ float Sbuf[2 * 4 * 2 * 32];
  __shared__ float c_lds[(MODE == 2) ? 32 * 64 * 9 : 4];   // [k][b][jj] pad9: 72KB

  // hoisted packed os for k = 8kq .. 8kq+7 (slot s <-> d = (s&3)+4hi+8*(s>>2))
  uint4 os_pk[8];
  {
    const unsigned short* osb = osB + ((size_t)bt * 64 + lane) * 8 + (size_t)(8 * kq) * 1024;
#pragma unroll
    for (int kk = 0; kk < 8; ++kk) os_pk[kk] = *(const uint4*)(osb + (size_t)kk * 1024);
  }

  float acc[4][16];
#pragma unroll
  for (int q = 0; q < 4; ++q)
#pragma unroll
    for (int s = 0; s < 16; ++s) acc[q][s] = 0.f;

  const unsigned short* waBase =
      WB + (size_t)j0 * 8192 + (b31 >> 4) * 256 + (b31 & 15) * 16 + 8 * hi + (size_t)kq * 2048;
  const unsigned short* xBase = XT + (size_t)j0 * 1024 + b * 16 + 8 * hi;

  uint4 a_cur[4], b_cur;
#pragma unroll
  for (int q = 0; q < 4; ++q) a_cur[q] = *(const uint4*)(waBase + q * 512);
  b_cur = *(const uint4*)(xBase);

  for (int jj = 0; jj < JCR; ++jj) {
    uint4 a_nxt[4], b_nxt;
    if (jj + 1 < JCR) {
#pragma unroll
      for (int q = 0; q < 4; ++q)
        a_nxt[q] = *(const uint4*)(waBase + (size_t)(jj + 1) * 8192 + q * 512);
      b_nxt = *(const uint4*)(xBase + (size_t)(jj + 1) * 1024);
    }

    f32x16 u[4];
#pragma unroll
    for (int q = 0; q < 4; ++q)
      u[q] = __builtin_amdgcn_mfma_f32_32x32x16_bf16(
          __builtin_bit_cast(short8v, a_cur[q]), __builtin_bit_cast(short8v, b_cur),
          zero16(), 0, 0, 0);

    float ee[4], eo[4];
    float Sp = 0.f;
#pragma unroll
    for (int q = 0; q < 4; ++q) {
      const unsigned int* o0 = (const unsigned int*)&os_pk[2 * q];
      const unsigned int* o1 = (const unsigned int*)&os_pk[2 * q + 1];
      float pe = 0.f, po = 0.f;
#pragma unroll
      for (int s = 0; s < 8; ++s) {
        const unsigned int w0 = o0[s >> 1], w1 = o1[s >> 1];
        pe = fmaf(u[q][s], bf2f((s & 1) ? (w0 >> 16) : (w0 & 0xffffu)), pe);
        po = fmaf(u[q][8 + s], bf2f((s & 1) ? (w1 >> 16) : (w1 & 0xffffu)), po);
      }
      pe += __shfl_xor(pe, 32);      // partner hi-half -> full dot over d
      po += __shfl_xor(po, 32);
      // logits O(+-8): skip max-subtraction (shift-invariant; validated r1-r15)
      ee[q] = __expf(pe);
      eo[q] = __expf(po);
      Sp += ee[q] + eo[q];
    }
    // cross-wave S reduction over the 4 kq waves (same bt)
    if (hi == 0) Sbuf[((jj & 1) * 8 + kq * 2 + bt) * 32 + b31] = Sp;
    __syncthreads();
    const int sb = (jj & 1) * 8;
    const float S = Sbuf[(sb + 0 * 2 + bt) * 32 + b31] + Sbuf[(sb + 1 * 2 + bt) * 32 + b31] +
                    Sbuf[(sb + 2 * 2 + bt) * 32 + b31] + Sbuf[(sb + 3 * 2 + bt) * 32 + b31];
    const float rS = __builtin_amdgcn_rcpf(S);
#pragma unroll
    for (int q = 0; q < 4; ++q) {
      const float ce = ee[q] * rS, co = eo[q] * rS;
#pragma unroll
      for (int s = 0; s < 8; ++s) {
        acc[q][s] = fmaf(ce, u[q][s], acc[q][s]);
        acc[q][8 + s] = fmaf(co, u[q][8 + s], acc[q][8 + s]);
      }
      if constexpr (MODE == 2) {
        if (hi == 0) {
          const int k0 = 8 * kq + 2 * q;
          c_lds[((k0)*64 + b) * 9 + jj] = ce;       // pad-9: conflict-free
          c_lds[((k0 + 1) * 64 + b) * 9 + jj] = co;
        }
      }
    }
#pragma unroll
    for (int q = 0; q < 4; ++q) a_cur[q] = a_nxt[q];
    b_cur = b_nxt;
  }

  // spart store, bf16-packed d-pairs
#pragma unroll
  for (int q = 0; q < 4; ++q) {
    const int keven = 8 * kq + 2 * q;
    unsigned int* se = spart_pk + (((size_t)b * NCH + ch) * 32 + keven) * 8 + 2 * hi;
    *(uint2*)se = make_uint2(cvtpk(acc[q][0], acc[q][1]), cvtpk(acc[q][2], acc[q][3]));
    *(uint2*)(se + 4) = make_uint2(cvtpk(acc[q][4], acc[q][5]), cvtpk(acc[q][6], acc[q][7]));
    unsigned int* so = se + 8;
    *(uint2*)so = make_uint2(cvtpk(acc[q][8], acc[q][9]), cvtpk(acc[q][10], acc[q][11]));
    *(uint2*)(so + 4) =
        make_uint2(cvtpk(acc[q][12], acc[q][13]), cvtpk(acc[q][14], acc[q][15]));
  }

  if constexpr (MODE == 2) {
    __syncthreads();
    // c transpose out: row r = k*64+b; 8 j's contiguous at outp[b][k][16+j0..]
#pragma unroll
    for (int m = 0; m < 4; ++m) {
      const int r = m * 512 + t;
      const int k = r >> 6, bb = r & 63;
      const float* cr = &c_lds[r * 9];
      float* orow = outp + ((size_t)bb * K_ + k) * 2064 + 16 + j0;
      *(float4*)orow = make_float4(cr[0], cr[1], cr[2], cr[3]);
      *(float4*)(orow + 4) = make_float4(cr[4], cr[5], cr[6], cr[7]);
    }
  }
}

// ---------------- squash: reduce packed spart (depth NCH) -> s, squash -> o.
// Wave per (b,k). Lane: h = d-pair (d = 2h, 2h+1), pg = lane>>3 (8 p-groups).
__global__ __launch_bounds__(256) void k_squash(const unsigned int* __restrict__ spart_pk,
                                                float* __restrict__ osum,
                                                unsigned short* __restrict__ osB,
                                                float* __restrict__ outp,
                                                int first, int final_) {
  const int t = threadIdx.x;
  const int wave = t >> 6, lane = t & 63;
  const int gw = blockIdx.x * 4 + wave;   // 0..B_*K_-1
  const int b = gw >> 5, k = gw & 31;
  const int h = lane & 7, pg = lane >> 3;
  float s0 = 0.f, s1 = 0.f;
#pragma unroll 8
  for (int p = pg; p < NCH; p += 8) {
    const unsigned int v = spart_pk[(((size_t)b * NCH + p) * 32 + k) * 8 + h];
    s0 += bf2f(v & 0xffffu);
    s1 += bf2f(v >> 16);
  }
  s0 += __shfl_xor(s0, 8);  s1 += __shfl_xor(s1, 8);
  s0 += __shfl_xor(s0, 16); s1 += __shfl_xor(s1, 16);
  s0 += __shfl_xor(s0, 32); s1 += __shfl_xor(s1, 32);
  float ss = s0 * s0 + s1 * s1;
  ss += __shfl_xor(ss, 1); ss += __shfl_xor(ss, 2); ss += __shfl_xor(ss, 4);
  const float scale = (ss / (1.f + ss)) * rsqrtf(ss + 1e-7f);
  const float ov0 = scale * s0, ov1 = scale * s1;
  if (final_) {
    if (pg == 0)
      *(float2*)(outp + ((size_t)b * K_ + k) * 2064 + 2 * h) = make_float2(ov0, ov1);
  } else {
    if (pg == 0) {
      float2 prev = make_float2(0.f, 0.f);
      if (!first) prev = *(const float2*)(osum + b * KD + k * 16 + 2 * h);
      const float ns0 = prev.x + ov0, ns1 = prev.y + ov1;
      *(float2*)(osum + b * KD + k * 16 + 2 * h) = make_float2(ns0, ns1);
      const int d0 = 2 * h;
      const int hi0 = (d0 >> 2) & 1;
      const int slot0 = (d0 & 3) + ((d0 >> 3) << 2);
      *(unsigned int*)(osB + (((size_t)k * 2 + (b >> 5)) * 64 + hi0 * 32 + (b & 31)) * 8 +
                       slot0) = cvtpk(ns0, ns1);
    }
  }
}

extern "C" void kernel_launch(void* const* d_in, const int* in_sizes, int n_in,
                              void* d_out, int out_size, void* d_ws, size_t ws_size,
                              hipStream_t stream) {
  const float* inp = (const float*)d_in[0];   // [64,2048,16]
  const float* W   = (const float*)d_in[1];   // [32,2048,16,16]
  float* outp = (float*)d_out;                // [64,32,2064]
  char* ws = (char*)d_ws;
  // ws: WB 32M @0 | XT 4M @32M | spart_pk 16M @36M | osum 128K @52M | osB 64K
  unsigned short* WB = (unsigned short*)ws;
  unsigned short* XT = (unsigned short*)(ws + (size_t)33554432);
  unsigned int* spart_pk = (unsigned int*)(ws + (size_t)37748736);
  float* osum  = (float*)(ws + (size_t)54525952);
  unsigned short* osB = (unsigned short*)(ws + (size_t)54525952 + 131072);

  k_prepX<<<512, 256, 0, stream>>>(inp, XT);
  // iter 0: c = 1/32, fused with W conversion (writes WB for iters 1-2)
  k_R0W<<<NCH, 512, 0, stream>>>(W, XT, WB, spart_pk);
  k_squash<<<B_ * K_ / 4, 256, 0, stream>>>(spart_pk, osum, osB, outp, 1, 0);
  // iter 1
  k_R<1><<<NCH, 512, 0, stream>>>(XT, WB, osB, spart_pk, nullptr);
  k_squash<<<B_ * K_ / 4, 256, 0, stream>>>(spart_pk, osum, osB, outp, 0, 0);
  // iter 2 (final): c -> outp via LDS transpose (no cT)
  k_R<2><<<NCH, 512, 0, stream>>>(XT, WB, osB, spart_pk, outp);
  k_squash<<<B_ * K_ / 4, 256, 0, stream>>>(spart_pk, osum, osB, outp, 0, 1);
}